// Round 2
// baseline (853.213 us; speedup 1.0000x reference)
//
#include <hip/hip_runtime.h>
#include <stdint.h>

#define B_ 4
#define S_ 2048
#define D_ 2048
#define H_ 2560
#define O_ 2048
#define M_ (B_*S_)   // 8192 rows
#define NCH 16       // scan S-chunks
#define LCH (S_/NCH) // 128

typedef __attribute__((ext_vector_type(8))) short bf16x8;
typedef __attribute__((ext_vector_type(4))) float f32x4;

typedef const __attribute__((address_space(1))) unsigned int* gp32;
typedef __attribute__((address_space(3))) unsigned int* lp32;

__device__ __forceinline__ void async_cp16(const unsigned short* g, unsigned short* l) {
    __builtin_amdgcn_global_load_lds((gp32)g, (lp32)l, 16, 0, 0);
}

__device__ __forceinline__ unsigned short f2bf(float f) {
    unsigned int x = __float_as_uint(f);
    x += 0x7fffu + ((x >> 16) & 1u);   // round-to-nearest-even
    return (unsigned short)(x >> 16);
}
__device__ __forceinline__ float bf2f(unsigned short s) {
    return __uint_as_float(((unsigned int)s) << 16);
}
__device__ __forceinline__ float4 ld_bf4(const unsigned short* p) {
    const uint2 u = *(const uint2*)p;
    float4 r;
    r.x = bf2f((unsigned short)(u.x & 0xffffu));
    r.y = bf2f((unsigned short)(u.x >> 16));
    r.z = bf2f((unsigned short)(u.y & 0xffffu));
    r.w = bf2f((unsigned short)(u.y >> 16));
    return r;
}
__device__ __forceinline__ float fast_sigmoid(float x) { return 1.0f / (1.0f + __expf(-x)); }
__device__ __forceinline__ float gelu_tanh(float x) {
    // jax.nn.gelu approximate=True
    float t = 0.7978845608028654f * (x + 0.044715f * x * x * x);
    float e = __expf(2.0f * t);
    float th = 1.0f - 2.0f / (e + 1.0f);
    return 0.5f * x * (1.0f + th);
}

// ---------------- cast x fp32 -> bf16 ----------------
__global__ void cast_x_kernel(const float* __restrict__ in, unsigned short* __restrict__ out, int n4) {
    int gid = blockIdx.x * 256 + threadIdx.x;
    if (gid >= n4) return;
    const float4 v = ((const float4*)in)[gid];
    union { unsigned short s[4]; uint2 u; } pk;
    pk.s[0] = f2bf(v.x); pk.s[1] = f2bf(v.y); pk.s[2] = f2bf(v.z); pk.s[3] = f2bf(v.w);
    ((uint2*)out)[gid] = pk.u;
}

// ---------------- transpose+cast: in [K,N] fp32 -> out [N,K] bf16 ----------------
__global__ void transpose_cast_kernel(const float* __restrict__ in, unsigned short* __restrict__ out,
                                      int K, int N) {
    __shared__ float tile[64][65];
    const int t = threadIdx.x;
    const int k0 = blockIdx.y * 64, n0 = blockIdx.x * 64;
    const int r = t >> 4, c4 = (t & 15) * 4;
    #pragma unroll
    for (int p = 0; p < 4; ++p) {
        const float4 v = *(const float4*)(in + (size_t)(k0 + p*16 + r) * N + n0 + c4);
        tile[p*16 + r][c4+0] = v.x;
        tile[p*16 + r][c4+1] = v.y;
        tile[p*16 + r][c4+2] = v.z;
        tile[p*16 + r][c4+3] = v.w;
    }
    __syncthreads();
    #pragma unroll
    for (int p = 0; p < 4; ++p) {
        const int nn = n0 + p*16 + r;
        union { unsigned short s[4]; uint2 u; } pk;
        #pragma unroll
        for (int j = 0; j < 4; ++j) pk.s[j] = f2bf(tile[c4 + j][p*16 + r]);
        *(uint2*)(out + (size_t)nn * K + k0 + c4) = pk.u;
    }
}

// ---------------- bf16 MFMA GEMM, 256x256 tile, BK=64, 8-phase schedule ----------------
// 512 threads = 8 waves (2M x 4N); per-wave output 128x64 = acc[8][4] f32x4.
// LDS 128 KiB: double-buffered A[256x64]+B[256x64] bf16, chunk-XOR swizzle on
// global source (linear global_load_lds dest), inverted on ds_read.
// 8 phases per 2 K-tiles; per phase: {ds_read subtile; 2x global_load_lds;
// [vmcnt(4) at P3/P7]; barrier; setprio(1); 16 MFMA; setprio(0); barrier}.
// Uniform 2 loads/phase staging windows (after buffer-death barriers):
//   P0-P1: B(t+1)->Bs1   (Bs1 dead after prev P6)
//   P2-P3: A(t+2)->As0   (As0 dead after P1)
//   P4-P5: B(t+2)->Bs0   (Bs0 dead after P2)
//   P6-P7: A(t+3)->As1   (As1 dead after P5)
// vmcnt(4) at end-P3 retires {A(t+1),B(t+1)} (publishes As1/Bs1 for P4);
// vmcnt(4) at end-P7 retires {A(t+2),B(t+2)} (publishes As0/Bs0 for next P0);
// never drains to 0 in the loop. No sched_barrier / no coarse lgkmcnt —
// plain-C++ ds_reads let the compiler emit fine-grained lgkmcnt interleave.
// MODE 0: N=5120: n<H -> left=bf16(gelu(v+b0)); n>=H -> rin=bf16(v+b1)
// MODE 1: N=5120: n<H -> r=bf16(sigmoid(v+b0)); n>=H -> i=bf16(sigmoid(v+b1))
// MODE 2: N=2048: out=fp32(v+b0)

#define LD_A(dst, base)                                                        \
    _Pragma("unroll")                                                          \
    for (int f = 0; f < 4; ++f) {                                              \
      dst[f][0] = *(const bf16x8*)((base) + rbaseA + f * 1024 + ch0);          \
      dst[f][1] = *(const bf16x8*)((base) + rbaseA + f * 1024 + ch1);          \
    }

#define LD_B(dst, base)                                                        \
    _Pragma("unroll")                                                          \
    for (int f = 0; f < 2; ++f) {                                              \
      dst[f][0] = *(const bf16x8*)((base) + rbaseB + f * 1024 + ch0);          \
      dst[f][1] = *(const bf16x8*)((base) + rbaseB + f * 1024 + ch1);          \
    }

#define MM(ar, br, i0, j0)                                                     \
    __builtin_amdgcn_s_setprio(1);                                             \
    _Pragma("unroll")                                                          \
    for (int ks = 0; ks < 2; ++ks)                                             \
      _Pragma("unroll")                                                        \
      for (int f = 0; f < 4; ++f)                                              \
        _Pragma("unroll")                                                      \
        for (int g = 0; g < 2; ++g)                                            \
          acc[(i0) + f][(j0) + g] = __builtin_amdgcn_mfma_f32_16x16x32_bf16(   \
              ar[f][ks], br[g][ks], acc[(i0) + f][(j0) + g], 0, 0, 0);         \
    __builtin_amdgcn_s_setprio(0);

// stage one half-tile (rows half*128 .. half*128+127) of tile k-offset kk
#define STG(gptr, kk, lbuf, half)                                              \
    async_cp16((gptr) + (size_t)(kk) + (size_t)((half)*2)   * gr64,            \
               (lbuf) + (half)*8192 + ldst);                                   \
    async_cp16((gptr) + (size_t)(kk) + (size_t)((half)*2+1) * gr64,            \
               (lbuf) + (half)*8192 + ldst + 4096);

#define BAR() __builtin_amdgcn_s_barrier()

template <int MODE>
__global__ __launch_bounds__(512, 2) void gemm_kernel(
        const unsigned short* __restrict__ A,
        const unsigned short* __restrict__ Bt,
        const int K,
        const float* __restrict__ bias0,
        const float* __restrict__ bias1,
        void* __restrict__ out0,
        void* __restrict__ out1)
{
    __shared__ __align__(16) unsigned short As0[256*64];
    __shared__ __align__(16) unsigned short As1[256*64];
    __shared__ __align__(16) unsigned short Bs0[256*64];
    __shared__ __align__(16) unsigned short Bs1[256*64];

    const int t = threadIdx.x;

    // bijective XCD swizzle (all grids here are %8 == 0)
    const int nx = gridDim.x;
    const int nwg = gridDim.x * gridDim.y;
    int lin = blockIdx.y * nx + blockIdx.x;
    lin = (lin & 7) * (nwg >> 3) + (lin >> 3);
    const int m0 = (lin / nx) * 256;
    const int n0 = (lin % nx) * 256;

    // staging: thread t covers row t>>3 (+64 per row-group), chunk (t&7)^(row&7)
    const int srow = t >> 3;                        // 0..63
    const int scol = ((t & 7) ^ (srow & 7)) * 8;
    const unsigned short* gA = A  + (size_t)(m0 + srow) * K + scol;
    const unsigned short* gB = Bt + (size_t)(n0 + srow) * K + scol;
    const size_t gr64 = (size_t)64 * K;             // 64-row step (elements)
    const int ldst = t * 8;                         // linear LDS dest (halfwords)

    const int lane = t & 63;
    const int w = t >> 6;          // 0..7
    const int wm = w >> 2;         // 0..1  -> rows wm*128..+128
    const int wn = w & 3;          // 0..3  -> cols wn*64..+64
    const int q = lane >> 4;       // k-quad 0..3
    const int l16 = lane & 15;

    const int rbaseA = (wm * 128 + l16) * 64;       // halfword offsets
    const int rbaseB = (wn * 64 + l16) * 64;
    const int ch0 = ((q)     ^ (l16 & 7)) * 8;      // swizzled k-chunks ks=0/1
    const int ch1 = ((q + 4) ^ (l16 & 7)) * 8;

    const int nt = K >> 6;   // 32 or 40 (always even)

    f32x4 acc[8][4];
    #pragma unroll
    for (int i = 0; i < 8; ++i)
        #pragma unroll
        for (int j = 0; j < 4; ++j)
            acc[i][j] = (f32x4){0.f, 0.f, 0.f, 0.f};

    bf16x8 a0[4][2], a1[4][2], b0[2][2], b1[2][2];

    // prologue: A(0),B(0) full; A(1) full (stays in flight, published at P3)
    STG(gA, 0, As0, 0); STG(gA, 0, As0, 1);
    STG(gB, 0, Bs0, 0); STG(gB, 0, Bs0, 1);
    STG(gA, 64, As1, 0); STG(gA, 64, As1, 1);
    asm volatile("s_waitcnt vmcnt(4)" ::: "memory");
    BAR();

    for (int tt = 0; tt < nt; tt += 2) {
        const size_t kb1 = (size_t)((tt + 1 < nt) ? (tt + 1) * 64 : 0);
        const size_t ka2 = (size_t)((tt + 2 < nt) ? (tt + 2) * 64 : 0);
        const size_t kb2 = ka2;
        const size_t ka3 = (size_t)((tt + 3 < nt) ? (tt + 3) * 64 : 0);

        // ---- P0: tile tt, quadrant m0n0 ----
        LD_A(a0, As0); LD_B(b0, Bs0);
        STG(gB, kb1, Bs1, 0);
        BAR();
        MM(a0, b0, 0, 0);
        BAR();
        // ---- P1: m1n0 ----
        LD_A(a1, As0 + 4096);
        STG(gB, kb1, Bs1, 1);
        BAR();
        MM(a1, b0, 4, 0);
        BAR();
        // ---- P2: m0n1 ----
        LD_B(b1, Bs0 + 2048);
        STG(gA, ka2, As0, 0);
        BAR();
        MM(a0, b1, 0, 2);
        BAR();
        // ---- P3: m1n1 ; publish As1/Bs1 for P4 ----
        STG(gA, ka2, As0, 1);
        asm volatile("s_waitcnt vmcnt(4)" ::: "memory");
        BAR();
        MM(a1, b1, 4, 2);
        BAR();
        // ---- P4: tile tt+1, m0n0 ----
        LD_A(a0, As1); LD_B(b0, Bs1);
        STG(gB, kb2, Bs0, 0);
        BAR();
        MM(a0, b0, 0, 0);
        BAR();
        // ---- P5: m1n0 ----
        LD_A(a1, As1 + 4096);
        STG(gB, kb2, Bs0, 1);
        BAR();
        MM(a1, b0, 4, 0);
        BAR();
        // ---- P6: m0n1 ----
        LD_B(b1, Bs1 + 2048);
        STG(gA, ka3, As1, 0);
        BAR();
        MM(a0, b1, 0, 2);
        BAR();
        // ---- P7: m1n1 ; publish As0/Bs0 for next P0 ----
        STG(gA, ka3, As1, 1);
        asm volatile("s_waitcnt vmcnt(4)" ::: "memory");
        BAR();
        MM(a1, b1, 4, 2);
        BAR();
    }
    asm volatile("s_waitcnt vmcnt(0)" ::: "memory");   // drain trailing dummies

    // epilogue: C/D layout col=lane&15, row=(lane>>4)*4+reg
    const int rb = q * 4;
    if (MODE == 2) {
        float* op = (float*)out0;
        #pragma unroll
        for (int i = 0; i < 8; ++i) {
            const int rr = m0 + wm * 128 + (i >> 2) * 64 + (i & 3) * 16 + rb;
            #pragma unroll
            for (int j = 0; j < 4; ++j) {
                const int cc = n0 + wn * 64 + (j >> 1) * 32 + (j & 1) * 16 + l16;
                const float bb = bias0[cc];
                #pragma unroll
                for (int jj = 0; jj < 4; ++jj)
                    op[(size_t)(rr + jj) * O_ + cc] = acc[i][j][jj] + bb;
            }
        }
    } else {
        // N=5120 split at H_=2560 is block-uniform (n0 multiple of 256)
        const bool left = (n0 < H_);
        const float* bias = left ? bias0 : bias1;
        unsigned short* op = (unsigned short*)(left ? out0 : out1);
        const int nb = left ? n0 : (n0 - H_);
        #pragma unroll
        for (int i = 0; i < 8; ++i) {
            const int rr = m0 + wm * 128 + (i >> 2) * 64 + (i & 3) * 16 + rb;
            #pragma unroll
            for (int j = 0; j < 4; ++j) {
                const int cc = nb + wn * 64 + (j >> 1) * 32 + (j & 1) * 16 + l16;
                const float bb = bias[cc];
                #pragma unroll
                for (int jj = 0; jj < 4; ++jj) {
                    float v = acc[i][j][jj] + bb;
                    if (MODE == 0) v = left ? gelu_tanh(v) : v;
                    else           v = fast_sigmoid(v);
                    op[(size_t)(rr + jj) * H_ + cc] = f2bf(v);
                }
            }
        }
    }
}

// ---------------- causal depthwise conv (width 4), bf16 in -> bf16 out ----------------
__global__ void conv_kernel(const unsigned short* __restrict__ rin,
                            const float* __restrict__ cw,
                            const float* __restrict__ cb,
                            unsigned short* __restrict__ ub)
{
    const int gid = blockIdx.x * 256 + threadIdx.x;   // (b, s/4, h/4)
    const int h = (gid % (H_/4)) * 4;
    const int tmp = gid / (H_/4);
    const int s0 = (tmp % (S_/4)) * 4;
    const int b = tmp / (S_/4);
    const unsigned short* base = rin + (size_t)b * S_ * H_ + h;
    float4 rows[7];
    #pragma unroll
    for (int idx = 0; idx < 7; ++idx) {
        const int s = s0 - 3 + idx;
        if (s >= 0) rows[idx] = ld_bf4(base + (size_t)s * H_);
        else        rows[idx] = make_float4(0.f, 0.f, 0.f, 0.f);
    }
    float4 w[4];
    #pragma unroll
    for (int j = 0; j < 4; ++j) w[j] = *(const float4*)(cw + j * H_ + h);
    const float4 bias = *(const float4*)(cb + h);
    #pragma unroll
    for (int p = 0; p < 4; ++p) {
        float ox = bias.x, oy = bias.y, oz = bias.z, ow = bias.w;
        #pragma unroll
        for (int j = 0; j < 4; ++j) {
            ox += w[j].x * rows[p + j].x;
            oy += w[j].y * rows[p + j].y;
            oz += w[j].z * rows[p + j].z;
            ow += w[j].w * rows[p + j].w;
        }
        const size_t oidx = (size_t)b * S_ * H_ + (size_t)(s0 + p) * H_ + h;
        union { unsigned short s4[4]; uint2 uu; } pk;
        pk.s4[0] = f2bf(ox); pk.s4[1] = f2bf(oy); pk.s4[2] = f2bf(oz); pk.s4[3] = f2bf(ow);
        *(uint2*)(ub + oidx) = pk.uu;
    }
}

// ---------------- chunked RG-LRU scan (3 passes) ----------------
__global__ void scan_pass1(const unsigned short* __restrict__ rg,
                           const unsigned short* __restrict__ ig,
                           const unsigned short* __restrict__ ub,
                           const float* __restrict__ lam,
                           float* __restrict__ Asum,
                           float* __restrict__ Hend)
{
    const int tid = blockIdx.x * 256 + threadIdx.x;  // (b*NCH + c)*H + h
    const int h = tid % H_;
    const int t2 = tid / H_;
    const int c = t2 % NCH;
    const int b = t2 / NCH;
    const float kh = -8.0f * log1pf(__expf(-lam[h]));
    size_t idx = ((size_t)b * S_ + (size_t)c * LCH) * H_ + h;
    float A = 1.f, hs = 0.f;
    #pragma unroll 4
    for (int s = 0; s < LCH; ++s, idx += H_) {
        const float rv = bf2f(rg[idx]);
        const float iv = bf2f(ig[idx]);
        const float uv = bf2f(ub[idx]);
        const float a = __expf(kh * rv);
        const float beta = sqrtf(fmaxf(1.f - a * a, 1e-12f));
        hs = a * hs + beta * iv * uv;
        A *= a;
    }
    Asum[tid] = A;
    Hend[tid] = hs;
}

__global__ void scan_pass2(const float* __restrict__ Asum, float* __restrict__ Hend) {
    const int tid = blockIdx.x * 256 + threadIdx.x;   // b*H + h
    const int h = tid % H_;
    const int b = tid / H_;
    float hin = 0.f;
    #pragma unroll
    for (int c = 0; c < NCH; ++c) {
        const int q = (b * NCH + c) * H_ + h;
        const float Ac = Asum[q];
        const float he = Hend[q];
        Hend[q] = hin;
        hin = he + Ac * hin;
    }
}

__global__ void scan_pass3(const unsigned short* __restrict__ rg,
                           const unsigned short* __restrict__ ig,
                           const unsigned short* __restrict__ ub,
                           const unsigned short* __restrict__ leftb,
                           const float* __restrict__ lam,
                           const float* __restrict__ Hin,
                           unsigned short* __restrict__ lrb)
{
    const int tid = blockIdx.x * 256 + threadIdx.x;
    const int h = tid % H_;
    const int t2 = tid / H_;
    const int c = t2 % NCH;
    const int b = t2 / NCH;
    const float kh = -8.0f * log1pf(__expf(-lam[h]));
    size_t idx = ((size_t)b * S_ + (size_t)c * LCH) * H_ + h;
    float hs = Hin[tid];
    #pragma unroll 4
    for (int s = 0; s < LCH; ++s, idx += H_) {
        const float rv = bf2f(rg[idx]);
        const float iv = bf2f(ig[idx]);
        const float uv = bf2f(ub[idx]);
        const float lf = bf2f(leftb[idx]);
        const float a = __expf(kh * rv);
        const float beta = sqrtf(fmaxf(1.f - a * a, 1e-12f));
        hs = a * hs + beta * iv * uv;
        lrb[idx] = f2bf(lf * hs);
    }
}

extern "C" void kernel_launch(void* const* d_in, const int* in_sizes, int n_in,
                              void* d_out, int out_size, void* d_ws, size_t ws_size,
                              hipStream_t stream)
{
    const float* x   = (const float*)d_in[0];
    const float* Wl  = (const float*)d_in[1];
    const float* bl  = (const float*)d_in[2];
    const float* Wr  = (const float*)d_in[3];
    const float* br  = (const float*)d_in[4];
    const float* cw  = (const float*)d_in[5];
    const float* cb  = (const float*)d_in[6];
    const float* Wa  = (const float*)d_in[7];
    const float* ba  = (const float*)d_in[8];
    const float* Wi  = (const float*)d_in[9];
    const float* bi  = (const float*)d_in[10];
    const float* lam = (const float*)d_in[11];
    const float* Wo  = (const float*)d_in[12];
    const float* bo  = (const float*)d_in[13];
    float* out = (float*)d_out;
    (void)in_sizes; (void)n_in; (void)out_size;

    const size_t wWlr = (size_t)2 * H_ * D_ * 2;   // 20.97 MB
    const size_t wWai = (size_t)2 * H_ * H_ * 2;   // 26.21 MB
    const size_t wWo  = (size_t)O_ * H_ * 2;       // 10.49 MB
    auto al = [](size_t b) { return (b + 255) & ~(size_t)255; };

    // choose batch-chunking so workspace fits: nchunk in {1,2,4}
    int nchunk = 4;
    for (int n = 1; n <= 4; n *= 2) {
        const size_t Mc = M_ / n;
        const size_t Bc = Mc / S_;
        const size_t need = al(wWlr) + al(wWai) + al(wWo)
                          + 4 * al(Mc * H_ * 2)
                          + 2 * al(Bc * NCH * H_ * 4);
        if (need <= ws_size) { nchunk = n; break; }
    }
    const int Mc = M_ / nchunk;
    const int Bc = Mc / S_;
    const size_t actB = (size_t)Mc * H_ * 2;

    char* p = (char*)d_ws;
    size_t off = 0;
    auto alloc = [&](size_t bytes) -> void* {
        void* q = p + off;
        off += al(bytes);
        return q;
    };
    unsigned short* WlrT  = (unsigned short*)alloc(wWlr);
    unsigned short* WaiT  = (unsigned short*)alloc(wWai);
    unsigned short* WoT   = (unsigned short*)alloc(wWo);
    unsigned short* slotX = (unsigned short*)alloc(actB);  // xb -> rgate -> lr
    unsigned short* slotL = (unsigned short*)alloc(actB);  // left
    unsigned short* slotR = (unsigned short*)alloc(actB);  // rin -> igate
    unsigned short* slotU = (unsigned short*)alloc(actB);  // u
    float* Asum = (float*)alloc((size_t)Bc * NCH * H_ * 4);
    float* Hend = (float*)alloc((size_t)Bc * NCH * H_ * 4);

    // weight transposes (once)
    transpose_cast_kernel<<<dim3(H_/64, D_/64), dim3(256), 0, stream>>>(Wl, WlrT, D_, H_);
    transpose_cast_kernel<<<dim3(H_/64, D_/64), dim3(256), 0, stream>>>(Wr, WlrT + (size_t)H_*D_, D_, H_);
    transpose_cast_kernel<<<dim3(H_/64, H_/64), dim3(256), 0, stream>>>(Wa, WaiT, H_, H_);
    transpose_cast_kernel<<<dim3(H_/64, H_/64), dim3(256), 0, stream>>>(Wi, WaiT + (size_t)H_*H_, H_, H_);
    transpose_cast_kernel<<<dim3(O_/64, H_/64), dim3(256), 0, stream>>>(Wo, WoT, H_, O_);

    for (int c = 0; c < nchunk; ++c) {
        const float* xc = x + (size_t)c * Mc * D_;
        float* outc = out + (size_t)c * Mc * O_;
        unsigned short* xb    = slotX;
        unsigned short* leftb = slotL;
        unsigned short* rinb  = slotR;
        unsigned short* ub    = slotU;
        unsigned short* rgb   = slotX;   // xb dead after GEMM1
        unsigned short* igb   = slotR;   // rinb dead after conv
        unsigned short* lrb   = slotX;   // in-place over rgate in pass 3

        cast_x_kernel<<<dim3(Mc*D_/4/256), dim3(256), 0, stream>>>(xc, xb, Mc*D_/4);
        gemm_kernel<0><<<dim3((2*H_)/256, Mc/256), dim3(512), 0, stream>>>(xb, WlrT, D_, bl, br, leftb, rinb);
        conv_kernel<<<dim3(Bc*S_*H_/16/256), dim3(256), 0, stream>>>(rinb, cw, cb, ub);
        gemm_kernel<1><<<dim3((2*H_)/256, Mc/256), dim3(512), 0, stream>>>(ub, WaiT, H_, ba, bi, rgb, igb);
        scan_pass1<<<dim3(Bc*NCH*H_/256), dim3(256), 0, stream>>>(rgb, igb, ub, lam, Asum, Hend);
        scan_pass2<<<dim3(Bc*H_/256), dim3(256), 0, stream>>>(Asum, Hend);
        scan_pass3<<<dim3(Bc*NCH*H_/256), dim3(256), 0, stream>>>(rgb, igb, ub, leftb, lam, Hend, lrb);
        gemm_kernel<2><<<dim3(O_/256, Mc/256), dim3(512), 0, stream>>>(lrb, WoT, H_, bo, nullptr, outc, nullptr);
    }
}

// Round 3
// 835.189 us; speedup vs baseline: 1.0216x; 1.0216x over previous
//
#include <hip/hip_runtime.h>
#include <stdint.h>

#define B_ 4
#define S_ 2048
#define D_ 2048
#define H_ 2560
#define O_ 2048
#define M_ (B_*S_)   // 8192 rows
#define NCH 16       // scan S-chunks
#define LCH (S_/NCH) // 128

typedef __attribute__((ext_vector_type(8))) short bf16x8;
typedef __attribute__((ext_vector_type(4))) float f32x4;

typedef const __attribute__((address_space(1))) unsigned int* gp32;
typedef __attribute__((address_space(3))) unsigned int* lp32;

__device__ __forceinline__ void async_cp16(const unsigned short* g, unsigned short* l) {
    __builtin_amdgcn_global_load_lds((gp32)g, (lp32)l, 16, 0, 0);
}

__device__ __forceinline__ unsigned short f2bf(float f) {
    unsigned int x = __float_as_uint(f);
    x += 0x7fffu + ((x >> 16) & 1u);   // round-to-nearest-even
    return (unsigned short)(x >> 16);
}
__device__ __forceinline__ float bf2f(unsigned short s) {
    return __uint_as_float(((unsigned int)s) << 16);
}
__device__ __forceinline__ float4 ld_bf4(const unsigned short* p) {
    const uint2 u = *(const uint2*)p;
    float4 r;
    r.x = bf2f((unsigned short)(u.x & 0xffffu));
    r.y = bf2f((unsigned short)(u.x >> 16));
    r.z = bf2f((unsigned short)(u.y & 0xffffu));
    r.w = bf2f((unsigned short)(u.y >> 16));
    return r;
}
__device__ __forceinline__ float fast_sigmoid(float x) { return 1.0f / (1.0f + __expf(-x)); }
__device__ __forceinline__ float gelu_tanh(float x) {
    // jax.nn.gelu approximate=True
    float t = 0.7978845608028654f * (x + 0.044715f * x * x * x);
    float e = __expf(2.0f * t);
    float th = 1.0f - 2.0f / (e + 1.0f);
    return 0.5f * x * (1.0f + th);
}

// ---------------- cast x fp32 -> bf16 ----------------
__global__ void cast_x_kernel(const float* __restrict__ in, unsigned short* __restrict__ out, int n4) {
    int gid = blockIdx.x * 256 + threadIdx.x;
    if (gid >= n4) return;
    const float4 v = ((const float4*)in)[gid];
    union { unsigned short s[4]; uint2 u; } pk;
    pk.s[0] = f2bf(v.x); pk.s[1] = f2bf(v.y); pk.s[2] = f2bf(v.z); pk.s[3] = f2bf(v.w);
    ((uint2*)out)[gid] = pk.u;
}

// ---------------- transpose+cast: in [K,N] fp32 -> out [N,K] bf16 ----------------
__global__ void transpose_cast_kernel(const float* __restrict__ in, unsigned short* __restrict__ out,
                                      int K, int N) {
    __shared__ float tile[64][65];
    const int t = threadIdx.x;
    const int k0 = blockIdx.y * 64, n0 = blockIdx.x * 64;
    const int r = t >> 4, c4 = (t & 15) * 4;
    #pragma unroll
    for (int p = 0; p < 4; ++p) {
        const float4 v = *(const float4*)(in + (size_t)(k0 + p*16 + r) * N + n0 + c4);
        tile[p*16 + r][c4+0] = v.x;
        tile[p*16 + r][c4+1] = v.y;
        tile[p*16 + r][c4+2] = v.z;
        tile[p*16 + r][c4+3] = v.w;
    }
    __syncthreads();
    #pragma unroll
    for (int p = 0; p < 4; ++p) {
        const int nn = n0 + p*16 + r;
        union { unsigned short s[4]; uint2 u; } pk;
        #pragma unroll
        for (int j = 0; j < 4; ++j) pk.s[j] = f2bf(tile[c4 + j][p*16 + r]);
        *(uint2*)(out + (size_t)nn * K + k0 + c4) = pk.u;
    }
}

// ---------------- bf16 MFMA GEMM, 128x128 tile, BK=64, XOR-swizzled LDS ----------------
// (proven 219us / 45% MfmaUtil structure; 3-4 blocks/CU give cross-block overlap)
// MODE 0: N=5120: n<H -> left=bf16(gelu(v+b0[n])); n>=H -> rin=bf16(v+b1[n-H])
// MODE 1: N=5120: n<H -> r=bf16(sigmoid(v+b0[n])); n>=H -> i=bf16(sigmoid(v+b1[n-H]))
// MODE 2: N=2048: out=fp32(v+b0[n])
template <int MODE>
__global__ __launch_bounds__(256, 4) void gemm_kernel(
        const unsigned short* __restrict__ A,
        const unsigned short* __restrict__ Bt,
        const int K,
        const float* __restrict__ bias0,
        const float* __restrict__ bias1,
        void* __restrict__ out0,
        void* __restrict__ out1)
{
    __shared__ __align__(16) unsigned short As[128*64];
    __shared__ __align__(16) unsigned short Bs[128*64];
    const int t = threadIdx.x;
    const int m0 = blockIdx.y * 128;
    const int n0 = blockIdx.x * 128;

    // staging: thread t covers rows {t>>3 + 32j}, k-chunk (t&7)^(row&7)
    const int srow = t >> 3;                         // 0..31
    const int csrc = ((t & 7) ^ (srow & 7)) * 8;     // element offset in row
    const unsigned short* gA = A  + (size_t)(m0 + srow) * K + csrc;
    const unsigned short* gB = Bt + (size_t)(n0 + srow) * K + csrc;
    unsigned short* lA = As + t * 8;                 // + j*2048 halfwords per call
    unsigned short* lB = Bs + t * 8;
    const size_t gstep = (size_t)32 * K;

    const int lane = t & 63;
    const int w = t >> 6;
    const int wm = (w >> 1) * 64;
    const int wn = (w & 1) * 64;
    const int q = lane >> 4;        // k-quad 0..3
    const int l16 = lane & 15;

    f32x4 acc[4][4];
    #pragma unroll
    for (int i = 0; i < 4; ++i)
        #pragma unroll
        for (int j = 0; j < 4; ++j)
            acc[i][j] = (f32x4){0.f, 0.f, 0.f, 0.f};

    for (int k0 = 0; k0 < K; k0 += 64) {
        #pragma unroll
        for (int j = 0; j < 4; ++j) {
            async_cp16(gA + j * gstep, lA + j * 2048);
            async_cp16(gB + j * gstep, lB + j * 2048);
        }
        gA += 64; gB += 64;
        __syncthreads();   // drains vmcnt for global_load_lds
        #pragma unroll
        for (int ks = 0; ks < 2; ++ks) {
            const int ch = ((q + ks * 4) ^ (l16 & 7)) * 8;   // swizzled chunk offset
            bf16x8 af[4], bfr[4];
            #pragma unroll
            for (int f = 0; f < 4; ++f)
                af[f]  = *(const bf16x8*)(As + (wm + f*16 + l16) * 64 + ch);
            #pragma unroll
            for (int f = 0; f < 4; ++f)
                bfr[f] = *(const bf16x8*)(Bs + (wn + f*16 + l16) * 64 + ch);
            #pragma unroll
            for (int fm = 0; fm < 4; ++fm)
                #pragma unroll
                for (int fn = 0; fn < 4; ++fn)
                    acc[fm][fn] = __builtin_amdgcn_mfma_f32_16x16x32_bf16(af[fm], bfr[fn], acc[fm][fn], 0, 0, 0);
        }
        __syncthreads();
    }

    const int rbase = q * 4;   // C/D: col=lane&15, row=(lane>>4)*4+reg
    #pragma unroll
    for (int fm = 0; fm < 4; ++fm) {
        #pragma unroll
        for (int fn = 0; fn < 4; ++fn) {
            const int cc = n0 + wn + fn * 16 + l16;
            #pragma unroll
            for (int j = 0; j < 4; ++j) {
                const int rr = m0 + wm + fm * 16 + rbase + j;
                float v = acc[fm][fn][j];
                if (MODE == 0) {
                    if (cc < H_) {
                        ((unsigned short*)out0)[(size_t)rr * H_ + cc] = f2bf(gelu_tanh(v + bias0[cc]));
                    } else {
                        const int c2 = cc - H_;
                        ((unsigned short*)out1)[(size_t)rr * H_ + c2] = f2bf(v + bias1[c2]);
                    }
                } else if (MODE == 1) {
                    if (cc < H_) {
                        ((unsigned short*)out0)[(size_t)rr * H_ + cc] = f2bf(fast_sigmoid(v + bias0[cc]));
                    } else {
                        const int c2 = cc - H_;
                        ((unsigned short*)out1)[(size_t)rr * H_ + c2] = f2bf(fast_sigmoid(v + bias1[c2]));
                    }
                } else {
                    ((float*)out0)[(size_t)rr * O_ + cc] = v + bias0[cc];
                }
            }
        }
    }
}

// ---------------- EXPERIMENT (GEMM3 only): 256x256 8-phase, ONE barrier/phase ----------------
// 512 thr = 8 waves (2Mx4N), per-wave 128x64 = acc[8][4]. LDS 128KiB dbuf.
// Region p = { ds_read subtile; stage 2 loads; MFMA quadrant; [vmcnt(4) at P3/P7]; barrier }.
// Single barrier/phase lets waves drift one region apart -> wave A's MFMA
// overlaps wave B's ds_reads (restores the cross-wave overlap the lock-step
// 2-barrier variant lacked). Compiler emits fine-grained lgkmcnt per use.
// Buffer-death: every stage-issue is >=1 barrier after its buffer's last
// ds_read region (reads complete in-region before that wave's MFMA waits).
// vmcnt(4) precedes the shared barrier publishing the staged data.
#define LDA2(dst, base)                                                        \
    _Pragma("unroll")                                                          \
    for (int f = 0; f < 4; ++f) {                                              \
      dst[f][0] = *(const bf16x8*)((base) + rbaseA + f * 1024 + ch0);          \
      dst[f][1] = *(const bf16x8*)((base) + rbaseA + f * 1024 + ch1);          \
    }
#define LDB2(dst, base)                                                        \
    _Pragma("unroll")                                                          \
    for (int f = 0; f < 2; ++f) {                                              \
      dst[f][0] = *(const bf16x8*)((base) + rbaseB + f * 1024 + ch0);          \
      dst[f][1] = *(const bf16x8*)((base) + rbaseB + f * 1024 + ch1);          \
    }
#define MM2(ar, br, i0, j0)                                                    \
    __builtin_amdgcn_s_setprio(1);                                             \
    _Pragma("unroll")                                                          \
    for (int ks = 0; ks < 2; ++ks)                                             \
      _Pragma("unroll")                                                        \
      for (int f = 0; f < 4; ++f)                                              \
        _Pragma("unroll")                                                      \
        for (int g = 0; g < 2; ++g)                                            \
          acc[(i0) + f][(j0) + g] = __builtin_amdgcn_mfma_f32_16x16x32_bf16(   \
              ar[f][ks], br[g][ks], acc[(i0) + f][(j0) + g], 0, 0, 0);         \
    __builtin_amdgcn_s_setprio(0);
#define STG2(gptr, kk, lbuf, half)                                             \
    async_cp16((gptr) + (size_t)(kk) + (size_t)((half)*2)   * gr64,            \
               (lbuf) + (half)*8192 + ldst);                                   \
    async_cp16((gptr) + (size_t)(kk) + (size_t)((half)*2+1) * gr64,            \
               (lbuf) + (half)*8192 + ldst + 4096);
#define BAR2() __builtin_amdgcn_s_barrier()

__global__ __launch_bounds__(512, 2) void gemm256_k2(
        const unsigned short* __restrict__ A,
        const unsigned short* __restrict__ Bt,
        const int K,
        const float* __restrict__ bias0,
        float* __restrict__ out0)
{
    __shared__ __align__(16) unsigned short As0[256*64];
    __shared__ __align__(16) unsigned short As1[256*64];
    __shared__ __align__(16) unsigned short Bs0[256*64];
    __shared__ __align__(16) unsigned short Bs1[256*64];

    const int t = threadIdx.x;

    // bijective XCD swizzle (grid 8x32 = 256 blocks, %8==0)
    const int nx = gridDim.x;
    const int nwg = gridDim.x * gridDim.y;
    int lin = blockIdx.y * nx + blockIdx.x;
    lin = (lin & 7) * (nwg >> 3) + (lin >> 3);
    const int m0 = (lin / nx) * 256;
    const int n0 = (lin % nx) * 256;

    const int srow = t >> 3;                        // 0..63
    const int scol = ((t & 7) ^ (srow & 7)) * 8;
    const unsigned short* gA = A  + (size_t)(m0 + srow) * K + scol;
    const unsigned short* gB = Bt + (size_t)(n0 + srow) * K + scol;
    const size_t gr64 = (size_t)64 * K;
    const int ldst = t * 8;

    const int lane = t & 63;
    const int w = t >> 6;
    const int wm = w >> 2;         // 0..1
    const int wn = w & 3;          // 0..3
    const int q = lane >> 4;
    const int l16 = lane & 15;

    const int rbaseA = (wm * 128 + l16) * 64;
    const int rbaseB = (wn * 64 + l16) * 64;
    const int ch0 = ((q)     ^ (l16 & 7)) * 8;
    const int ch1 = ((q + 4) ^ (l16 & 7)) * 8;

    const int nt = K >> 6;   // 40 (even)

    f32x4 acc[8][4];
    #pragma unroll
    for (int i = 0; i < 8; ++i)
        #pragma unroll
        for (int j = 0; j < 4; ++j)
            acc[i][j] = (f32x4){0.f, 0.f, 0.f, 0.f};

    bf16x8 a0[4][2], a1[4][2], b0[2][2], b1[2][2];

    // prologue: A(0),B(0) full; A(1) full (A(1) stays in flight past the wait)
    STG2(gA, 0, As0, 0); STG2(gA, 0, As0, 1);
    STG2(gB, 0, Bs0, 0); STG2(gB, 0, Bs0, 1);
    STG2(gA, 64, As1, 0); STG2(gA, 64, As1, 1);
    asm volatile("s_waitcnt vmcnt(4)" ::: "memory");
    BAR2();

    for (int tt = 0; tt < nt; tt += 2) {
        const size_t kb1 = (size_t)((tt + 1 < nt) ? (tt + 1) * 64 : 0);
        const size_t ka2 = (size_t)((tt + 2 < nt) ? (tt + 2) * 64 : 0);
        const size_t kb2 = ka2;
        const size_t ka3 = (size_t)((tt + 3 < nt) ? (tt + 3) * 64 : 0);

        // P0: tile tt m0n0
        LDA2(a0, As0); LDB2(b0, Bs0);
        STG2(gB, kb1, Bs1, 0);
        MM2(a0, b0, 0, 0);
        BAR2();
        // P1: m1n0
        LDA2(a1, As0 + 4096);
        STG2(gB, kb1, Bs1, 1);
        MM2(a1, b0, 4, 0);
        BAR2();
        // P2: m0n1
        LDB2(b1, Bs0 + 2048);
        STG2(gA, ka2, As0, 0);
        MM2(a0, b1, 0, 2);
        BAR2();
        // P3: m1n1 ; publish As1/Bs1 for P4
        STG2(gA, ka2, As0, 1);
        MM2(a1, b1, 4, 2);
        asm volatile("s_waitcnt vmcnt(4)" ::: "memory");
        BAR2();
        // P4: tile tt+1 m0n0
        LDA2(a0, As1); LDB2(b0, Bs1);
        STG2(gB, kb2, Bs0, 0);
        MM2(a0, b0, 0, 0);
        BAR2();
        // P5: m1n0
        LDA2(a1, As1 + 4096);
        STG2(gB, kb2, Bs0, 1);
        MM2(a1, b0, 4, 0);
        BAR2();
        // P6: m0n1
        LDB2(b1, Bs1 + 2048);
        STG2(gA, ka3, As1, 0);
        MM2(a0, b1, 0, 2);
        BAR2();
        // P7: m1n1 ; publish As0/Bs0 for next P0
        STG2(gA, ka3, As1, 1);
        MM2(a1, b1, 4, 2);
        asm volatile("s_waitcnt vmcnt(4)" ::: "memory");
        BAR2();
    }
    asm volatile("s_waitcnt vmcnt(0)" ::: "memory");   // drain trailing dummies

    // epilogue: C/D layout col=lane&15, row=(lane>>4)*4+reg ; out fp32 + bias
    const int rb = q * 4;
    #pragma unroll
    for (int i = 0; i < 8; ++i) {
        const int rr = m0 + wm * 128 + (i >> 2) * 64 + (i & 3) * 16 + rb;
        #pragma unroll
        for (int j = 0; j < 4; ++j) {
            const int cc = n0 + wn * 64 + (j >> 1) * 32 + (j & 1) * 16 + l16;
            const float bb = bias0[cc];
            #pragma unroll
            for (int jj = 0; jj < 4; ++jj)
                out0[(size_t)(rr + jj) * O_ + cc] = acc[i][j][jj] + bb;
        }
    }
}

// ---------------- causal depthwise conv (width 4), bf16 in -> bf16 out ----------------
__global__ void conv_kernel(const unsigned short* __restrict__ rin,
                            const float* __restrict__ cw,
                            const float* __restrict__ cb,
                            unsigned short* __restrict__ ub)
{
    const int gid = blockIdx.x * 256 + threadIdx.x;   // (b, s/4, h/4)
    const int h = (gid % (H_/4)) * 4;
    const int tmp = gid / (H_/4);
    const int s0 = (tmp % (S_/4)) * 4;
    const int b = tmp / (S_/4);
    const unsigned short* base = rin + (size_t)b * S_ * H_ + h;
    float4 rows[7];
    #pragma unroll
    for (int idx = 0; idx < 7; ++idx) {
        const int s = s0 - 3 + idx;
        if (s >= 0) rows[idx] = ld_bf4(base + (size_t)s * H_);
        else        rows[idx] = make_float4(0.f, 0.f, 0.f, 0.f);
    }
    float4 w[4];
    #pragma unroll
    for (int j = 0; j < 4; ++j) w[j] = *(const float4*)(cw + j * H_ + h);
    const float4 bias = *(const float4*)(cb + h);
    #pragma unroll
    for (int p = 0; p < 4; ++p) {
        float ox = bias.x, oy = bias.y, oz = bias.z, ow = bias.w;
        #pragma unroll
        for (int j = 0; j < 4; ++j) {
            ox += w[j].x * rows[p + j].x;
            oy += w[j].y * rows[p + j].y;
            oz += w[j].z * rows[p + j].z;
            ow += w[j].w * rows[p + j].w;
        }
        const size_t oidx = (size_t)b * S_ * H_ + (size_t)(s0 + p) * H_ + h;
        union { unsigned short s4[4]; uint2 uu; } pk;
        pk.s4[0] = f2bf(ox); pk.s4[1] = f2bf(oy); pk.s4[2] = f2bf(oz); pk.s4[3] = f2bf(ow);
        *(uint2*)(ub + oidx) = pk.uu;
    }
}

// ---------------- chunked RG-LRU scan (3 passes) ----------------
__global__ void scan_pass1(const unsigned short* __restrict__ rg,
                           const unsigned short* __restrict__ ig,
                           const unsigned short* __restrict__ ub,
                           const float* __restrict__ lam,
                           float* __restrict__ Asum,
                           float* __restrict__ Hend)
{
    const int tid = blockIdx.x * 256 + threadIdx.x;  // (b*NCH + c)*H + h
    const int h = tid % H_;
    const int t2 = tid / H_;
    const int c = t2 % NCH;
    const int b = t2 / NCH;
    const float kh = -8.0f * log1pf(__expf(-lam[h]));
    size_t idx = ((size_t)b * S_ + (size_t)c * LCH) * H_ + h;
    float A = 1.f, hs = 0.f;
    #pragma unroll 4
    for (int s = 0; s < LCH; ++s, idx += H_) {
        const float rv = bf2f(rg[idx]);
        const float iv = bf2f(ig[idx]);
        const float uv = bf2f(ub[idx]);
        const float a = __expf(kh * rv);
        const float beta = sqrtf(fmaxf(1.f - a * a, 1e-12f));
        hs = a * hs + beta * iv * uv;
        A *= a;
    }
    Asum[tid] = A;
    Hend[tid] = hs;
}

__global__ void scan_pass2(const float* __restrict__ Asum, float* __restrict__ Hend) {
    const int tid = blockIdx.x * 256 + threadIdx.x;   // b*H + h
    const int h = tid % H_;
    const int b = tid / H_;
    float hin = 0.f;
    #pragma unroll
    for (int c = 0; c < NCH; ++c) {
        const int q = (b * NCH + c) * H_ + h;
        const float Ac = Asum[q];
        const float he = Hend[q];
        Hend[q] = hin;
        hin = he + Ac * hin;
    }
}

__global__ void scan_pass3(const unsigned short* __restrict__ rg,
                           const unsigned short* __restrict__ ig,
                           const unsigned short* __restrict__ ub,
                           const unsigned short* __restrict__ leftb,
                           const float* __restrict__ lam,
                           const float* __restrict__ Hin,
                           unsigned short* __restrict__ lrb)
{
    const int tid = blockIdx.x * 256 + threadIdx.x;
    const int h = tid % H_;
    const int t2 = tid / H_;
    const int c = t2 % NCH;
    const int b = t2 / NCH;
    const float kh = -8.0f * log1pf(__expf(-lam[h]));
    size_t idx = ((size_t)b * S_ + (size_t)c * LCH) * H_ + h;
    float hs = Hin[tid];
    #pragma unroll 4
    for (int s = 0; s < LCH; ++s, idx += H_) {
        const float rv = bf2f(rg[idx]);
        const float iv = bf2f(ig[idx]);
        const float uv = bf2f(ub[idx]);
        const float lf = bf2f(leftb[idx]);
        const float a = __expf(kh * rv);
        const float beta = sqrtf(fmaxf(1.f - a * a, 1e-12f));
        hs = a * hs + beta * iv * uv;
        lrb[idx] = f2bf(lf * hs);
    }
}

extern "C" void kernel_launch(void* const* d_in, const int* in_sizes, int n_in,
                              void* d_out, int out_size, void* d_ws, size_t ws_size,
                              hipStream_t stream)
{
    const float* x   = (const float*)d_in[0];
    const float* Wl  = (const float*)d_in[1];
    const float* bl  = (const float*)d_in[2];
    const float* Wr  = (const float*)d_in[3];
    const float* br  = (const float*)d_in[4];
    const float* cw  = (const float*)d_in[5];
    const float* cb  = (const float*)d_in[6];
    const float* Wa  = (const float*)d_in[7];
    const float* ba  = (const float*)d_in[8];
    const float* Wi  = (const float*)d_in[9];
    const float* bi  = (const float*)d_in[10];
    const float* lam = (const float*)d_in[11];
    const float* Wo  = (const float*)d_in[12];
    const float* bo  = (const float*)d_in[13];
    float* out = (float*)d_out;
    (void)in_sizes; (void)n_in; (void)out_size;

    const size_t wWlr = (size_t)2 * H_ * D_ * 2;   // 20.97 MB
    const size_t wWai = (size_t)2 * H_ * H_ * 2;   // 26.21 MB
    const size_t wWo  = (size_t)O_ * H_ * 2;       // 10.49 MB
    auto al = [](size_t b) { return (b + 255) & ~(size_t)255; };

    // choose batch-chunking so workspace fits: nchunk in {1,2,4}
    int nchunk = 4;
    for (int n = 1; n <= 4; n *= 2) {
        const size_t Mc = M_ / n;
        const size_t Bc = Mc / S_;
        const size_t need = al(wWlr) + al(wWai) + al(wWo)
                          + 4 * al(Mc * H_ * 2)
                          + 2 * al(Bc * NCH * H_ * 4);
        if (need <= ws_size) { nchunk = n; break; }
    }
    const int Mc = M_ / nchunk;
    const int Bc = Mc / S_;
    const size_t actB = (size_t)Mc * H_ * 2;

    char* p = (char*)d_ws;
    size_t off = 0;
    auto alloc = [&](size_t bytes) -> void* {
        void* q = p + off;
        off += al(bytes);
        return q;
    };
    unsigned short* WlrT  = (unsigned short*)alloc(wWlr);
    unsigned short* WaiT  = (unsigned short*)alloc(wWai);
    unsigned short* WoT   = (unsigned short*)alloc(wWo);
    unsigned short* slotX = (unsigned short*)alloc(actB);  // xb -> rgate -> lr
    unsigned short* slotL = (unsigned short*)alloc(actB);  // left
    unsigned short* slotR = (unsigned short*)alloc(actB);  // rin -> igate
    unsigned short* slotU = (unsigned short*)alloc(actB);  // u
    float* Asum = (float*)alloc((size_t)Bc * NCH * H_ * 4);
    float* Hend = (float*)alloc((size_t)Bc * NCH * H_ * 4);

    // weight transposes (once)
    transpose_cast_kernel<<<dim3(H_/64, D_/64), dim3(256), 0, stream>>>(Wl, WlrT, D_, H_);
    transpose_cast_kernel<<<dim3(H_/64, D_/64), dim3(256), 0, stream>>>(Wr, WlrT + (size_t)H_*D_, D_, H_);
    transpose_cast_kernel<<<dim3(H_/64, H_/64), dim3(256), 0, stream>>>(Wa, WaiT, H_, H_);
    transpose_cast_kernel<<<dim3(H_/64, H_/64), dim3(256), 0, stream>>>(Wi, WaiT + (size_t)H_*H_, H_, H_);
    transpose_cast_kernel<<<dim3(O_/64, H_/64), dim3(256), 0, stream>>>(Wo, WoT, H_, O_);

    for (int c = 0; c < nchunk; ++c) {
        const float* xc = x + (size_t)c * Mc * D_;
        float* outc = out + (size_t)c * Mc * O_;
        unsigned short* xb    = slotX;
        unsigned short* leftb = slotL;
        unsigned short* rinb  = slotR;
        unsigned short* ub    = slotU;
        unsigned short* rgb   = slotX;   // xb dead after GEMM1
        unsigned short* igb   = slotR;   // rinb dead after conv
        unsigned short* lrb   = slotX;   // in-place over rgate in pass 3

        cast_x_kernel<<<dim3(Mc*D_/4/256), dim3(256), 0, stream>>>(xc, xb, Mc*D_/4);
        gemm_kernel<0><<<dim3((2*H_)/128, Mc/128), dim3(256), 0, stream>>>(xb, WlrT, D_, bl, br, leftb, rinb);
        conv_kernel<<<dim3(Bc*S_*H_/16/256), dim3(256), 0, stream>>>(rinb, cw, cb, ub);
        gemm_kernel<1><<<dim3((2*H_)/128, Mc/128), dim3(256), 0, stream>>>(ub, WaiT, H_, ba, bi, rgb, igb);
        scan_pass1<<<dim3(Bc*NCH*H_/256), dim3(256), 0, stream>>>(rgb, igb, ub, lam, Asum, Hend);
        scan_pass2<<<dim3(Bc*H_/256), dim3(256), 0, stream>>>(Asum, Hend);
        scan_pass3<<<dim3(Bc*NCH*H_/256), dim3(256), 0, stream>>>(rgb, igb, ub, leftb, lam, Hend, lrb);
        gemm256_k2<<<dim3(O_/256, Mc/256), dim3(512), 0, stream>>>(lrb, WoT, H_, bo, outc);
    }
}